// Round 13
// baseline (69.544 us; speedup 1.0000x reference)
//
#include <hip/hip_runtime.h>

typedef __attribute__((ext_vector_type(8))) short short8;
typedef __attribute__((ext_vector_type(4))) short short4v;
typedef __attribute__((ext_vector_type(4))) float f32x4;

#define MFMA_16x16x32_BF16(A, B, C) __builtin_amdgcn_mfma_f32_16x16x32_bf16(A, B, C, 0, 0, 0)

// float -> bf16 bits, round-to-nearest-even (inputs always finite here)
__device__ __forceinline__ unsigned short f2bf(float x) {
    unsigned int u = __builtin_bit_cast(unsigned int, x);
    u = (u + 0x7FFFu + ((u >> 16) & 1u)) >> 16;
    return (unsigned short)u;
}

// ===========================================================================
// PRIMARY PATH
// ===========================================================================

// ---------------------------------------------------------------------------
// Kernel 1a: pack Wk|Wq|Wv (fp32 [1024][64]) into MFMA-FRAGMENT-TILED bf16:
//   Wf[((kt*12 + c)*64 + lane)*8 + e] = W[k=32kt+8*(lane>>4)+e][n=16c+(lane&15)]
// (r5's wconv, proven correct.)  A B-frag read is one contiguous 1KB wave read.
// ---------------------------------------------------------------------------
__global__ __launch_bounds__(64) void wconv_frag(const float* __restrict__ Wk,
                                                 const float* __restrict__ Wq,
                                                 const float* __restrict__ Wv,
                                                 unsigned short* __restrict__ Wf) {
    const int kt = blockIdx.x;                     // 0..31
    const int c = blockIdx.y;                      // 0..11
    const int lane = threadIdx.x;
    const int lr = lane & 15, g = lane >> 4;
    const int n = 16 * c + lr;
    const float* W = (n < 64) ? Wk : (n < 128) ? Wq : Wv;
    const int col = n & 63;
    const int k0 = 32 * kt + 8 * g;
    short8 o;
#pragma unroll
    for (int e = 0; e < 8; ++e)
        o[e] = (short)f2bf(W[(size_t)(k0 + e) * 64 + col]);
    *(short8*)&Wf[(size_t)((kt * 12 + c) * 64 + lane) * 8] = o;
}

// ---------------------------------------------------------------------------
// Kernel 1b: X fp32 [16384][1024] -> Xf bf16 MFMA-A-FRAGMENT-TILED:
//   Xf[((rt*32 + kt)*64 + g*16 + lr)*8 + e] = X[rt*16+lr][32kt+8g+e]
// Pure dependency-free streaming copy: per wave-instruction the 64 lanes read
// a CONTIGUOUS 1KB of one X row; 16 independent loads/lane -> deep VMEM
// pipeline -> full HBM concurrency (what the strided staged variants never
// had).  The 67MB X read is paid ONCE here at copy-kernel bandwidth; proj
// then runs against the 33MB L3-resident Xf.
// ---------------------------------------------------------------------------
__global__ __launch_bounds__(256) void xconv_kernel(const float* __restrict__ X,
                                                    unsigned short* __restrict__ Xf) {
    const int rt = blockIdx.x;                     // 0..1023 (16-row tile)
    const int t = threadIdx.x;
    const int w = t >> 6, l = t & 63;
    const int r0 = rt * 16;
#pragma unroll
    for (int ri = 0; ri < 4; ++ri) {
        const int lrr = w * 4 + ri;                // row within tile, 0..15
        const float* row = X + (size_t)(r0 + lrr) * 1024;
#pragma unroll
        for (int i = 0; i < 4; ++i) {
            float4 v = *(const float4*)(row + i * 256 + l * 4);   // k = i*256+4l+j
            const int kt = i * 8 + (l >> 3);
            const int g = (l & 7) >> 1;
            const int e0 = 4 * (l & 1);
            uint2 o;
            o.x = (unsigned)f2bf(v.x) | ((unsigned)f2bf(v.y) << 16);
            o.y = (unsigned)f2bf(v.z) | ((unsigned)f2bf(v.w) << 16);
            *(uint2*)&Xf[(size_t)(((rt * 32 + kt) * 64) + g * 16 + lrr) * 8 + e0] = o;
        }
    }
}

// ---------------------------------------------------------------------------
// Kernel 2: QKV projection GEMM — r12's 2-barrier glds structure; single
// change vs r12's counters: BOTH operands come from fragment-tiled,
// L3-resident bf16 buffers (Xf/Wf).  Every glds: linear source, linear dest;
// LDS frag reads are contiguous-1KB (conflict-free, no swizzle); no in-loop
// conversion.  BM=32, BN=96, BK=64; 256 thr = 4 waves; grid 1024 = 4
// blocks/CU (TLP hides the now-L3-latency barrier drains).
// ---------------------------------------------------------------------------
__global__ __launch_bounds__(256, 4) void proj_kernel(const unsigned short* __restrict__ Xf,
                                                      const unsigned short* __restrict__ Wf,
                                                      unsigned short* __restrict__ Kb,
                                                      unsigned short* __restrict__ Qb,
                                                      unsigned short* __restrict__ Vtg) {
    __shared__ __attribute__((aligned(16))) unsigned short Al[4 * 512];    // 4 A-frags, 4KB
    __shared__ __attribute__((aligned(16))) unsigned short Wl[12 * 512];   // 12 W-frags, 12KB
    const int t = threadIdx.x;
    const int w = t >> 6, lane = t & 63, lr = lane & 15, g = lane >> 4;
    const int wr = w >> 1, wc = w & 1;
    const int rt2 = blockIdx.x >> 1, cb = blockIdx.x & 1;
    const int r0 = rt2 * 32;

    f32x4 acc[3] = {};

    for (int t16 = 0; t16 < 16; ++t16) {
        __syncthreads();                          // (1) prev compute done with LDS
        // ---- A: 4 frags (rtl in 0..1, ktl in 0..1), 1 glds/thread ----
        {
            const int f = t >> 6;                 // frag id 0..3
            const int rtl = f >> 1, ktl = f & 1;
            const unsigned short* src = Xf + ((size_t)(rt2 * 2 + rtl) * 32 + (t16 * 2 + ktl)) * 512 + (t & 63) * 8;
            __builtin_amdgcn_global_load_lds((const __attribute__((address_space(1))) void*)src,
                                             (__attribute__((address_space(3))) void*)&Al[t * 8],
                                             16, 0, 0);
        }
        // ---- W: 12 frags (ktl in 0..1 x cl in 0..5), 3 glds/thread ----
#pragma unroll
        for (int i = 0; i < 3; ++i) {
            const int q2 = t + 256 * i;
            const int f2 = q2 >> 6;               // 0..11
            const int ktl = (f2 >= 6) ? 1 : 0;
            const int cl = f2 - 6 * ktl;
            const unsigned short* src = Wf + ((size_t)(2 * t16 + ktl) * 12 + (cb * 6 + cl)) * 512 + (q2 & 63) * 8;
            __builtin_amdgcn_global_load_lds((const __attribute__((address_space(1))) void*)src,
                                             (__attribute__((address_space(3))) void*)&Wl[q2 * 8],
                                             16, 0, 0);
        }
        __syncthreads();                          // (2) drains vmcnt: tiles ready

        // ---- compute: frag-direct LDS reads (linear 1KB per wave) ----
        short8 af[2];
#pragma unroll
        for (int sub = 0; sub < 2; ++sub)
            af[sub] = *(const short8*)&Al[(wr * 2 + sub) * 512 + lane * 8];
#pragma unroll
        for (int c = 0; c < 3; ++c) {
#pragma unroll
            for (int sub = 0; sub < 2; ++sub) {
                short8 wf = *(const short8*)&Wl[(sub * 6 + wc * 3 + c) * 512 + lane * 8];
                acc[c] = MFMA_16x16x32_BF16(af[sub], wf, acc[c]);
            }
        }
    }

    // ---- epilogue: C/D layout col = lane&15 (W-col), row = 4*(lane>>4)+reg ----
    const int bb = r0 >> 11;                      // batch
    const int sb0 = (r0 & 2047) + 16 * wr + 4 * g;
    const int row = r0 + 16 * wr + 4 * g;
#pragma unroll
    for (int i = 0; i < 3; ++i) {
        const int cg = cb * 6 + wc * 3 + i;       // global col-tile 0..11
        if (cg < 4) {
#pragma unroll
            for (int r = 0; r < 4; ++r)
                Kb[(size_t)(row + r) * 64 + 16 * cg + lr] = f2bf(acc[i][r]);
        } else if (cg < 8) {
#pragma unroll
            for (int r = 0; r < 4; ++r)
                Qb[(size_t)(row + r) * 64 + 16 * (cg - 4) + lr] = f2bf(acc[i][r]);
        } else {
            const int h = 16 * (cg - 8) + lr;
            uint2 e;
            e.x = (unsigned)f2bf(acc[i][0]) | ((unsigned)f2bf(acc[i][1]) << 16);
            e.y = (unsigned)f2bf(acc[i][2]) | ((unsigned)f2bf(acc[i][3]) << 16);
            *(uint2*)(Vtg + (size_t)bb * 64 * 2048 + (size_t)h * 2048 + sb0) = e;
        }
    }
}

// ===========================================================================
// FALLBACK PATH (ws too small for Xf): r12's measured kernels, verbatim.
// ===========================================================================
__global__ __launch_bounds__(256) void wconv_sw(const float* __restrict__ Wk,
                                                const float* __restrict__ Wq,
                                                const float* __restrict__ Wv,
                                                unsigned short* __restrict__ Wt) {
    const int n = blockIdx.x;
    const float* W = (n < 64) ? Wk : (n < 128) ? Wq : Wv;
    const int col = n & 63;
    const int sw = (n & 7) << 3;
    for (int k = threadIdx.x; k < 1024; k += 256) {
        const int kd = (k & ~56) | ((k ^ sw) & 56);
        Wt[(size_t)n * 1024 + kd] = f2bf(W[(size_t)k * 64 + col]);
    }
}

__global__ __launch_bounds__(256) void proj_sw(const float* __restrict__ X,
                                               const unsigned short* __restrict__ Wt,
                                               unsigned short* __restrict__ Kb,
                                               unsigned short* __restrict__ Qb,
                                               unsigned short* __restrict__ Vtg) {
    __shared__ __attribute__((aligned(16))) float Af[32 * 64];
    __shared__ __attribute__((aligned(16))) unsigned short Wl[96 * 64];
    const int t = threadIdx.x;
    const int w = t >> 6, lane = t & 63, lr = lane & 15, g = lane >> 4;
    const int wr = w >> 1, wc = w & 1;
    const int rt = blockIdx.x >> 1, cb = blockIdx.x & 1;
    const int r0 = rt * 32;
    const int n0 = cb * 96;

    f32x4 acc[3] = {};

    for (int t16 = 0; t16 < 16; ++t16) {
        const int k0 = t16 * 64;
        __syncthreads();
#pragma unroll
        for (int i = 0; i < 2; ++i) {
            const int q = t + 256 * i;
            const int r = q >> 4, c = q & 15;
            const int csrc = c ^ ((r & 7) << 1);
            const float* src = X + (size_t)(r0 + r) * 1024 + k0 + csrc * 4;
            __builtin_amdgcn_global_load_lds((const __attribute__((address_space(1))) void*)src,
                                             (__attribute__((address_space(3))) void*)&Af[q * 4],
                                             16, 0, 0);
        }
#pragma unroll
        for (int i = 0; i < 3; ++i) {
            const int q = t + 256 * i;
            const unsigned short* src = Wt + (size_t)(n0 + (q >> 3)) * 1024 + k0 + (q & 7) * 8;
            __builtin_amdgcn_global_load_lds((const __attribute__((address_space(1))) void*)src,
                                             (__attribute__((address_space(3))) void*)&Wl[q * 8],
                                             16, 0, 0);
        }
        __syncthreads();

        const int ar = 16 * wr + lr;
        short8 af[2];
#pragma unroll
        for (int sub = 0; sub < 2; ++sub) {
            const int cs0 = (8 * sub + 2 * g) ^ ((lr & 7) << 1);
            const float* ap = &Af[ar * 64 + cs0 * 4];
            float4 v0 = *(const float4*)ap;
            float4 v1 = *(const float4*)(ap + 4);
            short8 a;
            a[0] = (short)f2bf(v0.x); a[1] = (short)f2bf(v0.y);
            a[2] = (short)f2bf(v0.z); a[3] = (short)f2bf(v0.w);
            a[4] = (short)f2bf(v1.x); a[5] = (short)f2bf(v1.y);
            a[6] = (short)f2bf(v1.z); a[7] = (short)f2bf(v1.w);
            af[sub] = a;
        }
#pragma unroll
        for (int c = 0; c < 3; ++c) {
            const int row = 48 * wc + 16 * c + lr;
#pragma unroll
            for (int sub = 0; sub < 2; ++sub) {
                const int cs = (4 * sub + g) ^ (lr & 7);
                short8 wf = *(const short8*)&Wl[row * 64 + cs * 8];
                acc[c] = MFMA_16x16x32_BF16(af[sub], wf, acc[c]);
            }
        }
    }

    const int bb = r0 >> 11;
    const int sb0 = (r0 & 2047) + 16 * wr + 4 * g;
    const int row = r0 + 16 * wr + 4 * g;
#pragma unroll
    for (int i = 0; i < 3; ++i) {
        const int cg = cb * 6 + wc * 3 + i;
        if (cg < 4) {
#pragma unroll
            for (int r = 0; r < 4; ++r)
                Kb[(size_t)(row + r) * 64 + 16 * cg + lr] = f2bf(acc[i][r]);
        } else if (cg < 8) {
#pragma unroll
            for (int r = 0; r < 4; ++r)
                Qb[(size_t)(row + r) * 64 + 16 * (cg - 4) + lr] = f2bf(acc[i][r]);
        } else {
            const int h = 16 * (cg - 8) + lr;
            uint2 e;
            e.x = (unsigned)f2bf(acc[i][0]) | ((unsigned)f2bf(acc[i][1]) << 16);
            e.y = (unsigned)f2bf(acc[i][2]) | ((unsigned)f2bf(acc[i][3]) << 16);
            *(uint2*)(Vtg + (size_t)bb * 64 * 2048 + (size_t)h * 2048 + sb0) = e;
        }
    }
}

// ---------------------------------------------------------------------------
// Kernel 3: causal flash attention, band-pair blocks (r2 measured-best,
// verbatim).  Block = bands {63-p (hi), p (lo)} of 32 q-rows each ->
// exactly 65 kv-steps per block.  8 waves split the 65 steps contiguously;
// K and V^T fragments load DIRECTLY from global (L2-resident) -> no LDS, no
// barriers in the main loop.  Partials merged in LDS at the end.
// ---------------------------------------------------------------------------
__global__ __launch_bounds__(512, 2) void attn_kernel(const unsigned short* __restrict__ Kb,
                                                      const unsigned short* __restrict__ Qb,
                                                      const unsigned short* __restrict__ Vtg,
                                                      float* __restrict__ out) {
    __shared__ __attribute__((aligned(16))) float Pacc[16][32][68];  // [slot][q][h] pad 68
    __shared__ float Pml[2][16][32];                                 // m / l per slot,q

    const int t = threadIdx.x;
    const int w = t >> 6, lane = t & 63;
    const int lr = lane & 15, g = lane >> 4;
    const int p = blockIdx.x, b = blockIdx.y;
    const int nhi = 64 - p;                      // steps for hi band
    const int q0h = (63 - p) * 32, q0l = p * 32;
    const size_t rowbase = (size_t)b * 2048;
    const size_t vbase = (size_t)b * 64 * 2048;
    const float NEG_INF = -__builtin_inff();
    const float SCALE2 = 0.03125f * 1.4426950408889634f;   // d^-0.5 * log2(e)

    // Q fragments (B-operand): [sub][hh]
    short8 qfH[2][2], qfL[2][2];
#pragma unroll
    for (int sub = 0; sub < 2; ++sub)
#pragma unroll
        for (int hh = 0; hh < 2; ++hh) {
            qfH[sub][hh] = *(const short8*)(Qb + (rowbase + q0h + 16 * sub + lr) * 64 + 32 * hh + 8 * g);
            qfL[sub][hh] = *(const short8*)(Qb + (rowbase + q0l + 16 * sub + lr) * 64 + 32 * hh + 8 * g);
        }

    f32x4 accH[2][4] = {}, accL[2][4] = {};
    float mH[2] = {NEG_INF, NEG_INF}, mL[2] = {NEG_INF, NEG_INF};
    float lH[2] = {0.f, 0.f}, lL[2] = {0.f, 0.f};

    const int s0 = (w * 65) >> 3, s1 = ((w + 1) * 65) >> 3;

    auto step = [&](int kv0, int q0, const short8 (&qf)[2][2],
                    f32x4 (&acc)[2][4], float (&m2)[2], float (&ls)[2]) {
        short8 kf[2][2];
#pragma unroll
        for (int f = 0; f < 2; ++f)
#pragma unroll
            for (int hh = 0; hh < 2; ++hh)
                kf[f][hh] = *(const short8*)(Kb + (rowbase + kv0 + 16 * f + lr) * 64 + 32 * hh + 8 * g);
        short8 vf[4];
#pragma unroll
        for (int fh = 0; fh < 4; ++fh) {
            const unsigned short* vp = Vtg + vbase + (size_t)(16 * fh + lr) * 2048 + kv0 + 4 * g;
            short4v v0 = *(const short4v*)vp;
            short4v v1 = *(const short4v*)(vp + 16);
            short8 vv;
            vv[0] = v0[0]; vv[1] = v0[1]; vv[2] = v0[2]; vv[3] = v0[3];
            vv[4] = v1[0]; vv[5] = v1[1]; vv[6] = v1[2]; vv[7] = v1[3];
            vf[fh] = vv;
        }
#pragma unroll
        for (int sub = 0; sub < 2; ++sub) {
            f32x4 sv[2];
#pragma unroll
            for (int f = 0; f < 2; ++f) {
                f32x4 x = {};
                x = MFMA_16x16x32_BF16(kf[f][0], qf[sub][0], x);
                x = MFMA_16x16x32_BF16(kf[f][1], qf[sub][1], x);
                sv[f] = x;
            }
            const int q = q0 + 16 * sub + lr;
            float pvv[8], tmax = NEG_INF;
#pragma unroll
            for (int f = 0; f < 2; ++f)
#pragma unroll
                for (int r = 0; r < 4; ++r) {
                    int kp = kv0 + 16 * f + 4 * g + r;
                    float sc = sv[f][r] * SCALE2;
                    sc = (kp <= q) ? sc : NEG_INF;
                    pvv[4 * f + r] = sc;
                    tmax = fmaxf(tmax, sc);
                }
            tmax = fmaxf(tmax, __shfl_xor(tmax, 16));
            tmax = fmaxf(tmax, __shfl_xor(tmax, 32));
            float mnew = fmaxf(m2[sub], tmax);     // finite: kv0 <= q0 <= q always
            float alpha = exp2f(m2[sub] - mnew);
            float psum = 0.f;
            short8 pf;
#pragma unroll
            for (int e = 0; e < 8; ++e) {
                float pe = exp2f(pvv[e] - mnew);
                psum += pe;
                pf[e] = (short)f2bf(pe);
            }
            psum += __shfl_xor(psum, 16);
            psum += __shfl_xor(psum, 32);
            ls[sub] = ls[sub] * alpha + psum;
            m2[sub] = mnew;
#pragma unroll
            for (int fh = 0; fh < 4; ++fh) {
                acc[sub][fh][0] *= alpha; acc[sub][fh][1] *= alpha;
                acc[sub][fh][2] *= alpha; acc[sub][fh][3] *= alpha;
                acc[sub][fh] = MFMA_16x16x32_BF16(vf[fh], pf, acc[sub][fh]);
            }
        }
    };

    const int ehi = (s1 < nhi) ? s1 : nhi;
    for (int s = s0; s < ehi; ++s) step(s * 32, q0h, qfH, accH, mH, lH);
    const int slo = (s0 > nhi) ? s0 : nhi;
    for (int s = slo; s < s1; ++s) step((s - nhi) * 32, q0l, qfL, accL, mL, lL);

#pragma unroll
    for (int bnd = 0; bnd < 2; ++bnd) {
        const f32x4 (&acc)[2][4] = bnd ? accL : accH;
        const float (&m2)[2] = bnd ? mL : mH;
        const float (&ls)[2] = bnd ? lL : lH;
        const int slot = bnd * 8 + w;
#pragma unroll
        for (int sub = 0; sub < 2; ++sub) {
#pragma unroll
            for (int fh = 0; fh < 4; ++fh)
                *(f32x4*)&Pacc[slot][16 * sub + lr][16 * fh + 4 * g] = acc[sub][fh];
            if (g == 0) {
                Pml[0][slot][16 * sub + lr] = m2[sub];
                Pml[1][slot][16 * sub + lr] = ls[sub];
            }
        }
    }
    __syncthreads();

    {
        const int tb = t >> 8, t2 = t & 255;
        const int qq = t2 & 31, hb = (t2 >> 5) * 8;
        float mw[8], M = NEG_INF;
#pragma unroll
        for (int wv = 0; wv < 8; ++wv) {
            mw[wv] = Pml[0][tb * 8 + wv][qq];
            M = fmaxf(M, mw[wv]);
        }
        float wgt[8], L = 0.f;
#pragma unroll
        for (int wv = 0; wv < 8; ++wv) {
            wgt[wv] = exp2f(mw[wv] - M);           // exp2(-inf)=0 for idle waves
            L += wgt[wv] * Pml[1][tb * 8 + wv][qq];
        }
        f32x4 o0 = {}, o1 = {};
#pragma unroll
        for (int wv = 0; wv < 8; ++wv) {
            f32x4 a0 = *(const f32x4*)&Pacc[tb * 8 + wv][qq][hb];
            f32x4 a1 = *(const f32x4*)&Pacc[tb * 8 + wv][qq][hb + 4];
            o0 += wgt[wv] * a0;
            o1 += wgt[wv] * a1;
        }
        const float invL = 1.f / L;
        o0 *= invL; o1 *= invL;
        const int q0 = tb ? q0l : q0h;
        float* op = out + (rowbase + q0 + qq) * 64 + hb;
        *(f32x4*)op = o0;
        *(f32x4*)(op + 4) = o1;
    }
}

// ---------------------------------------------------------------------------
extern "C" void kernel_launch(void* const* d_in, const int* in_sizes, int n_in,
                              void* d_out, int out_size, void* d_ws, size_t ws_size,
                              hipStream_t stream) {
    const float* X  = (const float*)d_in[0];
    const float* Wk = (const float*)d_in[1];
    const float* Wq = (const float*)d_in[2];
    const float* Wv = (const float*)d_in[3];
    float* out = (float*)d_out;

    const size_t XF_SHORTS = (size_t)16384 * 1024;           // 33.55 MB
    const size_t WF_SHORTS = (size_t)32 * 12 * 64 * 8;       // 384 KB
    const size_t KQV_SHORTS = (size_t)16384 * 64;            // 2 MB each
    const size_t need = (XF_SHORTS + WF_SHORTS + 3 * KQV_SHORTS) * 2;

    if (ws_size >= need) {
        unsigned short* Wf  = (unsigned short*)d_ws;
        unsigned short* Xf  = Wf + WF_SHORTS;
        unsigned short* Kb  = Xf + XF_SHORTS;
        unsigned short* Qb  = Kb + KQV_SHORTS;
        unsigned short* Vtg = Qb + KQV_SHORTS;

        wconv_frag<<<dim3(32, 12), dim3(64), 0, stream>>>(Wk, Wq, Wv, Wf);
        xconv_kernel<<<dim3(1024), dim3(256), 0, stream>>>(X, Xf);
        proj_kernel<<<dim3(1024), dim3(256), 0, stream>>>(Xf, Wf, Kb, Qb, Vtg);
        attn_kernel<<<dim3(32, 8), dim3(512), 0, stream>>>(Kb, Qb, Vtg, out);
    } else {
        unsigned short* Wt  = (unsigned short*)d_ws;          // 192*1024 (swizzled)
        unsigned short* Kb  = Wt + 192 * 1024;
        unsigned short* Qb  = Kb + KQV_SHORTS;
        unsigned short* Vtg = Qb + KQV_SHORTS;

        wconv_sw<<<dim3(192), dim3(256), 0, stream>>>(Wk, Wq, Wv, Wt);
        proj_sw<<<dim3(1024), dim3(256), 0, stream>>>(X, Wt, Kb, Qb, Vtg);
        attn_kernel<<<dim3(32, 8), dim3(512), 0, stream>>>(Kb, Qb, Vtg, out);
    }
}

// Round 14
// 67.589 us; speedup vs baseline: 1.0289x; 1.0289x over previous
//
#include <hip/hip_runtime.h>

typedef __attribute__((ext_vector_type(8))) short short8;
typedef __attribute__((ext_vector_type(4))) short short4v;
typedef __attribute__((ext_vector_type(4))) float f32x4;

#define MFMA_16x16x32_BF16(A, B, C) __builtin_amdgcn_mfma_f32_16x16x32_bf16(A, B, C, 0, 0, 0)

// float -> bf16 bits, round-to-nearest-even (inputs always finite here)
__device__ __forceinline__ unsigned short f2bf(float x) {
    unsigned int u = __builtin_bit_cast(unsigned int, x);
    u = (u + 0x7FFFu + ((u >> 16) & 1u)) >> 16;
    return (unsigned short)u;
}

// ---------------------------------------------------------------------------
// Kernel 1: pack Wk|Wq|Wv (fp32 [1024][64]) into MFMA-FRAGMENT-TILED bf16:
//   Wf[((kt*12 + c)*64 + lane)*8 + e] = W[k=32kt+8*(lane>>4)+e][n=16c+(lane&15)]
// (r5's wconv, proven correct.)  A B-frag read is one contiguous 1KB wave read.
// ---------------------------------------------------------------------------
__global__ __launch_bounds__(64) void wconv_frag(const float* __restrict__ Wk,
                                                 const float* __restrict__ Wq,
                                                 const float* __restrict__ Wv,
                                                 unsigned short* __restrict__ Wf) {
    const int kt = blockIdx.x;                     // 0..31
    const int c = blockIdx.y;                      // 0..11
    const int lane = threadIdx.x;
    const int lr = lane & 15, g = lane >> 4;
    const int n = 16 * c + lr;
    const float* W = (n < 64) ? Wk : (n < 128) ? Wq : Wv;
    const int col = n & 63;
    const int k0 = 32 * kt + 8 * g;
    short8 o;
#pragma unroll
    for (int e = 0; e < 8; ++e)
        o[e] = (short)f2bf(W[(size_t)(k0 + e) * 64 + col]);
    *(short8*)&Wf[(size_t)((kt * 12 + c) * 64 + lane) * 8] = o;
}

// ---------------------------------------------------------------------------
// Kernel 2: QKV projection GEMM — CONTIGUOUS-STAGING design (DRAM-locality
// fix).  Every prior proj read X as 256B chunks at 4KB stride (DRAM
// row-buffer efficiency ~30% -> the persistent ~1.7-2.5 TB/s wall that no
// barrier/TLP/pipeline change moved).  Here block = 32 rows x BN=192 full:
// its A-tile is a CONTIGUOUS 128KB of X.  Phase 1 stages it with a 2-deep
// static register ring (each thread: contiguous 512B; each 128B batch = one
// L2 line), converts, ds_writes into fragment-tiled LDS (frag stride 520
// shorts: 16B-aligned, compute reads are canonical lane-linear 1KB/wave ->
// conflict-free).  ONE barrier.  Phase 2 is BARRIER-FREE: 32 k-steps, W
// frags ping-pong straight from L2-resident Wf into regs (no LDS for W).
// Grid 512 = 2 blocks/CU (65KB LDS): one block's HBM staging overlaps the
// other's L2+MFMA phase.  Outputs: Kb/Qb [16384][64]; Vtg[b][64][2048].
// ---------------------------------------------------------------------------
__global__ __launch_bounds__(256) void proj_kernel(const float* __restrict__ X,
                                                   const unsigned short* __restrict__ Wf,
                                                   unsigned short* __restrict__ Kb,
                                                   unsigned short* __restrict__ Qb,
                                                   unsigned short* __restrict__ Vtg) {
    __shared__ __attribute__((aligned(16))) unsigned short Al[2 * 32 * 520];  // 65KB frag-tiled
    const int t = threadIdx.x;
    const int w = t >> 6, lane = t & 63, lr = lane & 15, g = lane >> 4;
    const int wr = w >> 1, wc = w & 1;             // row-tile / col-half
    const int r0 = blockIdx.x * 32;

    // ---- Phase 1: stage 128KB contiguous X -> bf16 frag-tiled LDS ----
    const int rowl = t >> 3;                       // 0..31
    const int rtl = rowl >> 4, lrow = rowl & 15;
    const int kc = t & 7;                          // 512B column-chunk id
    const float* xrow = X + (size_t)(r0 + rowl) * 1024 + kc * 128;

    float4 ra0[8], ra1[8];                         // 2-deep ring, static names
#define LOADB(RA, B)                                                        \
    { _Pragma("unroll")                                                     \
      for (int j = 0; j < 8; ++j) RA[j] = *(const float4*)(xrow + (B) * 32 + 4 * j); }
#define WRITEB(RA, B)                                                       \
    {                                                                       \
        const int kt_ = kc * 4 + (B);                                       \
        unsigned short* fb = &Al[(rtl * 32 + kt_) * 520];                   \
        _Pragma("unroll")                                                   \
        for (int gg = 0; gg < 4; ++gg) {                                    \
            float4 v0 = RA[2 * gg], v1 = RA[2 * gg + 1];                    \
            uint4 o;                                                        \
            o.x = (unsigned)f2bf(v0.x) | ((unsigned)f2bf(v0.y) << 16);      \
            o.y = (unsigned)f2bf(v0.z) | ((unsigned)f2bf(v0.w) << 16);      \
            o.z = (unsigned)f2bf(v1.x) | ((unsigned)f2bf(v1.y) << 16);      \
            o.w = (unsigned)f2bf(v1.z) | ((unsigned)f2bf(v1.w) << 16);      \
            *(uint4*)&fb[(gg * 16 + lrow) * 8] = o;                         \
        }                                                                   \
    }
    LOADB(ra0, 0) LOADB(ra1, 1)
    WRITEB(ra0, 0) LOADB(ra0, 2)
    WRITEB(ra1, 1) LOADB(ra1, 3)
    WRITEB(ra0, 2) WRITEB(ra1, 3)
#undef WRITEB
#undef LOADB
    __syncthreads();                               // ONE barrier in the kernel

    // ---- Phase 2: barrier-free compute; W frags ping-pong from L2 ----
    f32x4 acc[6] = {};
    const int wc6 = wc * 6;
    short8 wrA[6], wrB[6];
#define LOADW(WR, KT)                                                       \
    { _Pragma("unroll")                                                     \
      for (int c = 0; c < 6; ++c)                                           \
          WR[c] = *(const short8*)&Wf[(((KT) * 12 + wc6 + c) * 64 + lane) * 8]; }
#define MFMA6(WR, KT)                                                       \
    {                                                                       \
        short8 af = *(const short8*)&Al[(wr * 32 + (KT)) * 520 + lane * 8]; \
        _Pragma("unroll")                                                   \
        for (int c = 0; c < 6; ++c) acc[c] = MFMA_16x16x32_BF16(af, WR[c], acc[c]); \
    }
    LOADW(wrA, 0)
    for (int kt = 0; kt < 32; kt += 2) {
        LOADW(wrB, kt + 1)
        MFMA6(wrA, kt)
        if (kt + 2 < 32) LOADW(wrA, kt + 2)
        MFMA6(wrB, kt + 1)
    }
#undef MFMA6
#undef LOADW

    // ---- epilogue: C/D layout col = lane&15 (W-col), row = 4*(lane>>4)+reg ----
    const int bb = r0 >> 11;                      // batch
    const int sb0 = (r0 & 2047) + 16 * wr + 4 * g;
    const int row = r0 + 16 * wr + 4 * g;
#pragma unroll
    for (int i = 0; i < 6; ++i) {
        const int cg = wc6 + i;                   // global col-tile 0..11
        if (cg < 4) {
#pragma unroll
            for (int r = 0; r < 4; ++r)
                Kb[(size_t)(row + r) * 64 + 16 * cg + lr] = f2bf(acc[i][r]);
        } else if (cg < 8) {
#pragma unroll
            for (int r = 0; r < 4; ++r)
                Qb[(size_t)(row + r) * 64 + 16 * (cg - 4) + lr] = f2bf(acc[i][r]);
        } else {
            const int h = 16 * (cg - 8) + lr;
            uint2 e;
            e.x = (unsigned)f2bf(acc[i][0]) | ((unsigned)f2bf(acc[i][1]) << 16);
            e.y = (unsigned)f2bf(acc[i][2]) | ((unsigned)f2bf(acc[i][3]) << 16);
            *(uint2*)(Vtg + (size_t)bb * 64 * 2048 + (size_t)h * 2048 + sb0) = e;
        }
    }
}

// ---------------------------------------------------------------------------
// Kernel 3: causal flash attention, band-pair blocks (r2 measured-best,
// verbatim).  Block = bands {63-p (hi), p (lo)} of 32 q-rows each ->
// exactly 65 kv-steps per block.  8 waves split the 65 steps contiguously;
// K and V^T fragments load DIRECTLY from global (L2-resident) -> no LDS, no
// barriers in the main loop.  Partials merged in LDS at the end.
// ---------------------------------------------------------------------------
__global__ __launch_bounds__(512, 2) void attn_kernel(const unsigned short* __restrict__ Kb,
                                                      const unsigned short* __restrict__ Qb,
                                                      const unsigned short* __restrict__ Vtg,
                                                      float* __restrict__ out) {
    __shared__ __attribute__((aligned(16))) float Pacc[16][32][68];  // [slot][q][h] pad 68
    __shared__ float Pml[2][16][32];                                 // m / l per slot,q

    const int t = threadIdx.x;
    const int w = t >> 6, lane = t & 63;
    const int lr = lane & 15, g = lane >> 4;
    const int p = blockIdx.x, b = blockIdx.y;
    const int nhi = 64 - p;                      // steps for hi band
    const int q0h = (63 - p) * 32, q0l = p * 32;
    const size_t rowbase = (size_t)b * 2048;
    const size_t vbase = (size_t)b * 64 * 2048;
    const float NEG_INF = -__builtin_inff();
    const float SCALE2 = 0.03125f * 1.4426950408889634f;   // d^-0.5 * log2(e)

    // Q fragments (B-operand): [sub][hh]
    short8 qfH[2][2], qfL[2][2];
#pragma unroll
    for (int sub = 0; sub < 2; ++sub)
#pragma unroll
        for (int hh = 0; hh < 2; ++hh) {
            qfH[sub][hh] = *(const short8*)(Qb + (rowbase + q0h + 16 * sub + lr) * 64 + 32 * hh + 8 * g);
            qfL[sub][hh] = *(const short8*)(Qb + (rowbase + q0l + 16 * sub + lr) * 64 + 32 * hh + 8 * g);
        }

    f32x4 accH[2][4] = {}, accL[2][4] = {};
    float mH[2] = {NEG_INF, NEG_INF}, mL[2] = {NEG_INF, NEG_INF};
    float lH[2] = {0.f, 0.f}, lL[2] = {0.f, 0.f};

    const int s0 = (w * 65) >> 3, s1 = ((w + 1) * 65) >> 3;

    auto step = [&](int kv0, int q0, const short8 (&qf)[2][2],
                    f32x4 (&acc)[2][4], float (&m2)[2], float (&ls)[2]) {
        short8 kf[2][2];
#pragma unroll
        for (int f = 0; f < 2; ++f)
#pragma unroll
            for (int hh = 0; hh < 2; ++hh)
                kf[f][hh] = *(const short8*)(Kb + (rowbase + kv0 + 16 * f + lr) * 64 + 32 * hh + 8 * g);
        short8 vf[4];
#pragma unroll
        for (int fh = 0; fh < 4; ++fh) {
            const unsigned short* vp = Vtg + vbase + (size_t)(16 * fh + lr) * 2048 + kv0 + 4 * g;
            short4v v0 = *(const short4v*)vp;
            short4v v1 = *(const short4v*)(vp + 16);
            short8 vv;
            vv[0] = v0[0]; vv[1] = v0[1]; vv[2] = v0[2]; vv[3] = v0[3];
            vv[4] = v1[0]; vv[5] = v1[1]; vv[6] = v1[2]; vv[7] = v1[3];
            vf[fh] = vv;
        }
#pragma unroll
        for (int sub = 0; sub < 2; ++sub) {
            f32x4 sv[2];
#pragma unroll
            for (int f = 0; f < 2; ++f) {
                f32x4 x = {};
                x = MFMA_16x16x32_BF16(kf[f][0], qf[sub][0], x);
                x = MFMA_16x16x32_BF16(kf[f][1], qf[sub][1], x);
                sv[f] = x;
            }
            const int q = q0 + 16 * sub + lr;
            float pvv[8], tmax = NEG_INF;
#pragma unroll
            for (int f = 0; f < 2; ++f)
#pragma unroll
                for (int r = 0; r < 4; ++r) {
                    int kp = kv0 + 16 * f + 4 * g + r;
                    float sc = sv[f][r] * SCALE2;
                    sc = (kp <= q) ? sc : NEG_INF;
                    pvv[4 * f + r] = sc;
                    tmax = fmaxf(tmax, sc);
                }
            tmax = fmaxf(tmax, __shfl_xor(tmax, 16));
            tmax = fmaxf(tmax, __shfl_xor(tmax, 32));
            float mnew = fmaxf(m2[sub], tmax);     // finite: kv0 <= q0 <= q always
            float alpha = exp2f(m2[sub] - mnew);
            float psum = 0.f;
            short8 pf;
#pragma unroll
            for (int e = 0; e < 8; ++e) {
                float pe = exp2f(pvv[e] - mnew);
                psum += pe;
                pf[e] = (short)f2bf(pe);
            }
            psum += __shfl_xor(psum, 16);
            psum += __shfl_xor(psum, 32);
            ls[sub] = ls[sub] * alpha + psum;
            m2[sub] = mnew;
#pragma unroll
            for (int fh = 0; fh < 4; ++fh) {
                acc[sub][fh][0] *= alpha; acc[sub][fh][1] *= alpha;
                acc[sub][fh][2] *= alpha; acc[sub][fh][3] *= alpha;
                acc[sub][fh] = MFMA_16x16x32_BF16(vf[fh], pf, acc[sub][fh]);
            }
        }
    };

    const int ehi = (s1 < nhi) ? s1 : nhi;
    for (int s = s0; s < ehi; ++s) step(s * 32, q0h, qfH, accH, mH, lH);
    const int slo = (s0 > nhi) ? s0 : nhi;
    for (int s = slo; s < s1; ++s) step((s - nhi) * 32, q0l, qfL, accL, mL, lL);

#pragma unroll
    for (int bnd = 0; bnd < 2; ++bnd) {
        const f32x4 (&acc)[2][4] = bnd ? accL : accH;
        const float (&m2)[2] = bnd ? mL : mH;
        const float (&ls)[2] = bnd ? lL : lH;
        const int slot = bnd * 8 + w;
#pragma unroll
        for (int sub = 0; sub < 2; ++sub) {
#pragma unroll
            for (int fh = 0; fh < 4; ++fh)
                *(f32x4*)&Pacc[slot][16 * sub + lr][16 * fh + 4 * g] = acc[sub][fh];
            if (g == 0) {
                Pml[0][slot][16 * sub + lr] = m2[sub];
                Pml[1][slot][16 * sub + lr] = ls[sub];
            }
        }
    }
    __syncthreads();

    {
        const int tb = t >> 8, t2 = t & 255;
        const int qq = t2 & 31, hb = (t2 >> 5) * 8;
        float mw[8], M = NEG_INF;
#pragma unroll
        for (int wv = 0; wv < 8; ++wv) {
            mw[wv] = Pml[0][tb * 8 + wv][qq];
            M = fmaxf(M, mw[wv]);
        }
        float wgt[8], L = 0.f;
#pragma unroll
        for (int wv = 0; wv < 8; ++wv) {
            wgt[wv] = exp2f(mw[wv] - M);           // exp2(-inf)=0 for idle waves
            L += wgt[wv] * Pml[1][tb * 8 + wv][qq];
        }
        f32x4 o0 = {}, o1 = {};
#pragma unroll
        for (int wv = 0; wv < 8; ++wv) {
            f32x4 a0 = *(const f32x4*)&Pacc[tb * 8 + wv][qq][hb];
            f32x4 a1 = *(const f32x4*)&Pacc[tb * 8 + wv][qq][hb + 4];
            o0 += wgt[wv] * a0;
            o1 += wgt[wv] * a1;
        }
        const float invL = 1.f / L;
        o0 *= invL; o1 *= invL;
        const int q0 = tb ? q0l : q0h;
        float* op = out + (rowbase + q0 + qq) * 64 + hb;
        *(f32x4*)op = o0;
        *(f32x4*)(op + 4) = o1;
    }
}

// ---------------------------------------------------------------------------
extern "C" void kernel_launch(void* const* d_in, const int* in_sizes, int n_in,
                              void* d_out, int out_size, void* d_ws, size_t ws_size,
                              hipStream_t stream) {
    const float* X  = (const float*)d_in[0];
    const float* Wk = (const float*)d_in[1];
    const float* Wq = (const float*)d_in[2];
    const float* Wv = (const float*)d_in[3];
    float* out = (float*)d_out;

    unsigned short* Wf  = (unsigned short*)d_ws;       // 32*12*64*8 = 196608 bf16
    unsigned short* Kb  = Wf + 196608;                 // [16384][64] bf16
    unsigned short* Qb  = Kb + 16384 * 64;
    unsigned short* Vtg = Qb + 16384 * 64;             // [8][64][2048] bf16 (V^T)

    wconv_frag<<<dim3(32, 12), dim3(64), 0, stream>>>(Wk, Wq, Wv, Wf);
    proj_kernel<<<dim3(512), dim3(256), 0, stream>>>(X, Wf, Kb, Qb, Vtg);
    attn_kernel<<<dim3(32, 8), dim3(512), 0, stream>>>(Kb, Qb, Vtg, out);
}

// Round 15
// 49.036 us; speedup vs baseline: 1.4182x; 1.3784x over previous
//
#include <hip/hip_runtime.h>

typedef __attribute__((ext_vector_type(8))) short short8;
typedef __attribute__((ext_vector_type(4))) float f32x4;

#define MFMA_16x16x32_BF16(A, B, C) __builtin_amdgcn_mfma_f32_16x16x32_bf16(A, B, C, 0, 0, 0)

// float -> bf16 bits, round-to-nearest-even (inputs always finite here)
__device__ __forceinline__ unsigned short f2bf(float x) {
    unsigned int u = __builtin_bit_cast(unsigned int, x);
    u = (u + 0x7FFFu + ((u >> 16) & 1u)) >> 16;
    return (unsigned short)u;
}

// ---------------------------------------------------------------------------
// Kernel 1: pack Wk|Wq|Wv (fp32 [1024][64]) -> Wt bf16 [192][1024] transposed,
// with the proj LDS bank-swizzle PRE-BAKED: within each 64-k tile, 8-short
// chunk c holds logical chunk c ^ (n&7).  (G21: glds writes LDS linearly, so
// the conflict-free permutation must come from the source.)
// ---------------------------------------------------------------------------
__global__ __launch_bounds__(256) void wconv_kernel(const float* __restrict__ Wk,
                                                    const float* __restrict__ Wq,
                                                    const float* __restrict__ Wv,
                                                    unsigned short* __restrict__ Wt) {
    const int n = blockIdx.x;                       // 0..191
    const float* W = (n < 64) ? Wk : (n < 128) ? Wq : Wv;
    const int col = n & 63;
    const int sw = (n & 7) << 3;
    for (int k = threadIdx.x; k < 1024; k += 256) {
        const int kd = (k & ~56) | ((k ^ sw) & 56);   // XOR chunk bits 3..5
        Wt[(size_t)n * 1024 + kd] = f2bf(W[(size_t)k * 64 + col]);
    }
}

// ---------------------------------------------------------------------------
// Kernel 2: QKV projection GEMM — r10 verbatim (best measured ~34us):
// 2-phase pipeline with COUNTED-VMCNT barrier.  BM=32, BN=192, BK=64;
// 512 thr = 8 waves; grid 512 = 2 blocks/CU.  The single change vs r10 is
// the V epilogue target layout (Vt2 sigma-interleaved; same write cost).
// ---------------------------------------------------------------------------
__global__ __launch_bounds__(512, 4) void proj_kernel(const float* __restrict__ X,
                                                      const unsigned short* __restrict__ Wt,
                                                      unsigned short* __restrict__ Kb,
                                                      unsigned short* __restrict__ Qb,
                                                      unsigned short* __restrict__ Vt2) {
    __shared__ __attribute__((aligned(16))) unsigned short Wl[2][192 * 64];  // glds dbuf
    __shared__ __attribute__((aligned(16))) unsigned short Al[2][32 * 72];   // pad 64->72
    const int t = threadIdx.x;
    const int w = t >> 6, lane = t & 63, lr = lane & 15, g = lane >> 4;
    const int rw = w >> 2, cw = w & 3;
    const int r0 = blockIdx.x * 32;

    f32x4 acc[3] = {};

    // A staging coords: row = t>>4 (0..31), chunk = t&15 (4 floats)
    const int ar = t >> 4, ac = (t & 15) * 4;
    const float* xsrc = X + (size_t)(r0 + ar) * 1024 + ac;

    // ---- prologue ----
    float4 fly = *(const float4*)xsrc;                     // A(0)
    uint2 aw;
    aw.x = (unsigned)f2bf(fly.x) | ((unsigned)f2bf(fly.y) << 16);
    aw.y = (unsigned)f2bf(fly.z) | ((unsigned)f2bf(fly.w) << 16);
    *(uint2*)&Al[0][ar * 72 + ac] = aw;
#pragma unroll
    for (int i = 0; i < 3; ++i) {                          // W(0) -> Wl[0]
        const int q = t + 512 * i;
        const unsigned short* src = Wt + (size_t)(q >> 3) * 1024 + (q & 7) * 8;
        __builtin_amdgcn_global_load_lds((const __attribute__((address_space(1))) void*)src,
                                         (__attribute__((address_space(3))) void*)&Wl[0][q * 8],
                                         16, 0, 0);
    }
    __builtin_amdgcn_sched_barrier(0);                     // keep A-issue younger than glds
    fly = *(const float4*)(xsrc + 64);                     // A(1) — flies across barrier
    asm volatile("s_waitcnt vmcnt(1) lgkmcnt(0)" ::: "memory");
    __builtin_amdgcn_s_barrier();                          // tiles t=0 ready

    for (int t16 = 0; t16 < 16; ++t16) {
        const int cur = t16 & 1;
        if (t16 < 15) {
            // ---- convert A(t+1): auto-wait drains exactly that load ----
            aw.x = (unsigned)f2bf(fly.x) | ((unsigned)f2bf(fly.y) << 16);
            aw.y = (unsigned)f2bf(fly.z) | ((unsigned)f2bf(fly.w) << 16);
            *(uint2*)&Al[cur ^ 1][ar * 72 + ac] = aw;
            const int k1 = (t16 + 1) * 64;
#pragma unroll
            for (int i = 0; i < 3; ++i) {
                const int q = t + 512 * i;
                const unsigned short* src = Wt + (size_t)(q >> 3) * 1024 + k1 + (q & 7) * 8;
                __builtin_amdgcn_global_load_lds((const __attribute__((address_space(1))) void*)src,
                                                 (__attribute__((address_space(3))) void*)&Wl[cur ^ 1][q * 8],
                                                 16, 0, 0);
            }
            __builtin_amdgcn_sched_barrier(0);             // pin: glds older than A-issue
            const int anext = (t16 + 2 < 15) ? (t16 + 2) : 15;
            fly = *(const float4*)(xsrc + anext * 64);
        }

        // ---- compute tile t from buf cur ----
        short8 af[2];
        af[0] = *(const short8*)&Al[cur][(16 * rw + lr) * 72 + 8 * g];
        af[1] = *(const short8*)&Al[cur][(16 * rw + lr) * 72 + 32 + 8 * g];
#pragma unroll
        for (int c = 0; c < 3; ++c) {
            const int row = 48 * cw + 16 * c + lr;
#pragma unroll
            for (int sub = 0; sub < 2; ++sub) {
                const int cs = (4 * sub + g) ^ (lr & 7);     // un-swizzle
                short8 wf = *(const short8*)&Wl[cur][row * 64 + cs * 8];
                acc[c] = MFMA_16x16x32_BF16(af[sub], wf, acc[c]);
            }
        }
        // ---- counted-vmcnt barrier: W(t+1) drained, A prefetch stays live ----
        asm volatile("s_waitcnt vmcnt(1) lgkmcnt(0)" ::: "memory");
        __builtin_amdgcn_s_barrier();
    }

    // ---- epilogue: C/D layout col = lane&15 (W-col), row = 4*(lane>>4)+reg ----
    const int bb = r0 >> 11;                      // batch
    const int row = r0 + 16 * rw + 4 * g;
#pragma unroll
    for (int i = 0; i < 3; ++i) {
        const int cg = cw * 3 + i;                // global col-tile 0..11
        if (cg < 4) {
#pragma unroll
            for (int r = 0; r < 4; ++r)
                Kb[(size_t)(row + r) * 64 + 16 * cg + lr] = f2bf(acc[i][r]);
        } else if (cg < 8) {
#pragma unroll
            for (int r = 0; r < 4; ++r)
                Qb[(size_t)(row + r) * 64 + 16 * (cg - 4) + lr] = f2bf(acc[i][r]);
        } else {
            // Vt2 sigma-interleaved: [b][h][kt][g][e], e<4 -> kv=32kt+4g+e,
            // e>=4 -> kv=32kt+16+4g+(e-4).  Here kt=(r0&2047)>>5, e0=4*rw.
            const int h = 16 * (cg - 8) + lr;
            uint2 e;
            e.x = (unsigned)f2bf(acc[i][0]) | ((unsigned)f2bf(acc[i][1]) << 16);
            e.y = (unsigned)f2bf(acc[i][2]) | ((unsigned)f2bf(acc[i][3]) << 16);
            *(uint2*)(Vt2 + (size_t)bb * 64 * 2048 + (size_t)h * 2048
                      + ((r0 & 2047) >> 5) * 32 + g * 8 + 4 * rw) = e;
        }
    }
}

// ---------------------------------------------------------------------------
// Kernel 3: causal flash attention, band-pair blocks (r2 structure, best
// measured) + 2-step load batching + 16B V-frag loads (Vt2 layout).
// Block = bands {63-p (hi), p (lo)} of 32 q-rows each -> exactly 65 kv-steps.
// 8 waves split the 65 steps contiguously; K/V frags direct from global
// (L2-resident), loads for a PAIR of steps issued together so step-2's
// loads fly under step-1's compute (in-order vmcnt auto-waits).  Partials
// merged in LDS at the end.
// ---------------------------------------------------------------------------
__global__ __launch_bounds__(512, 2) void attn_kernel(const unsigned short* __restrict__ Kb,
                                                      const unsigned short* __restrict__ Qb,
                                                      const unsigned short* __restrict__ Vt2,
                                                      float* __restrict__ out) {
    __shared__ __attribute__((aligned(16))) float Pacc[16][32][68];  // [slot][q][h] pad 68
    __shared__ float Pml[2][16][32];                                 // m / l per slot,q

    const int t = threadIdx.x;
    const int w = t >> 6, lane = t & 63;
    const int lr = lane & 15, g = lane >> 4;
    const int p = blockIdx.x, b = blockIdx.y;
    const int nhi = 64 - p;                      // steps for hi band
    const int q0h = (63 - p) * 32, q0l = p * 32;
    const size_t rowbase = (size_t)b * 2048;
    const size_t vbase = (size_t)b * 64 * 2048;
    const float NEG_INF = -__builtin_inff();
    const float SCALE2 = 0.03125f * 1.4426950408889634f;   // d^-0.5 * log2(e)

    // Q fragments (B-operand): [sub][hh]
    short8 qfH[2][2], qfL[2][2];
#pragma unroll
    for (int sub = 0; sub < 2; ++sub)
#pragma unroll
        for (int hh = 0; hh < 2; ++hh) {
            qfH[sub][hh] = *(const short8*)(Qb + (rowbase + q0h + 16 * sub + lr) * 64 + 32 * hh + 8 * g);
            qfL[sub][hh] = *(const short8*)(Qb + (rowbase + q0l + 16 * sub + lr) * 64 + 32 * hh + 8 * g);
        }

    f32x4 accH[2][4] = {}, accL[2][4] = {};
    float mH[2] = {NEG_INF, NEG_INF}, mL[2] = {NEG_INF, NEG_INF};
    float lH[2] = {0.f, 0.f}, lL[2] = {0.f, 0.f};

    const int s0 = (w * 65) >> 3, s1 = ((w + 1) * 65) >> 3;

    auto loadS = [&](int kv0, short8 (&kf)[2][2], short8 (&vf)[4]) {
#pragma unroll
        for (int f = 0; f < 2; ++f)
#pragma unroll
            for (int hh = 0; hh < 2; ++hh)
                kf[f][hh] = *(const short8*)(Kb + (rowbase + kv0 + 16 * f + lr) * 64 + 32 * hh + 8 * g);
        // Vt2: one contiguous 16B per frag; e-map identical to P's sigma(g,e)
#pragma unroll
        for (int fh = 0; fh < 4; ++fh)
            vf[fh] = *(const short8*)(Vt2 + vbase + (size_t)(16 * fh + lr) * 2048 + (kv0 >> 5) * 32 + 8 * g);
    };

    auto comp = [&](int kv0, int q0, const short8 (&qf)[2][2],
                    const short8 (&kf)[2][2], const short8 (&vf)[4],
                    f32x4 (&acc)[2][4], float (&m2)[2], float (&ls)[2]) {
#pragma unroll
        for (int sub = 0; sub < 2; ++sub) {
            f32x4 sv[2];
#pragma unroll
            for (int f = 0; f < 2; ++f) {
                f32x4 x = {};
                x = MFMA_16x16x32_BF16(kf[f][0], qf[sub][0], x);
                x = MFMA_16x16x32_BF16(kf[f][1], qf[sub][1], x);
                sv[f] = x;
            }
            const int q = q0 + 16 * sub + lr;
            float pvv[8], tmax = NEG_INF;
#pragma unroll
            for (int f = 0; f < 2; ++f)
#pragma unroll
                for (int r = 0; r < 4; ++r) {
                    int kp = kv0 + 16 * f + 4 * g + r;
                    float sc = sv[f][r] * SCALE2;
                    sc = (kp <= q) ? sc : NEG_INF;
                    pvv[4 * f + r] = sc;
                    tmax = fmaxf(tmax, sc);
                }
            tmax = fmaxf(tmax, __shfl_xor(tmax, 16));
            tmax = fmaxf(tmax, __shfl_xor(tmax, 32));
            float mnew = fmaxf(m2[sub], tmax);     // finite: kv0 <= q0 <= q always
            float alpha = exp2f(m2[sub] - mnew);
            float psum = 0.f;
            short8 pf;
#pragma unroll
            for (int e = 0; e < 8; ++e) {
                float pe = exp2f(pvv[e] - mnew);
                psum += pe;
                pf[e] = (short)f2bf(pe);
            }
            psum += __shfl_xor(psum, 16);
            psum += __shfl_xor(psum, 32);
            ls[sub] = ls[sub] * alpha + psum;
            m2[sub] = mnew;
#pragma unroll
            for (int fh = 0; fh < 4; ++fh) {
                acc[sub][fh][0] *= alpha; acc[sub][fh][1] *= alpha;
                acc[sub][fh][2] *= alpha; acc[sub][fh][3] *= alpha;
                acc[sub][fh] = MFMA_16x16x32_BF16(vf[fh], pf, acc[sub][fh]);
            }
        }
    };

    short8 kfA[2][2], vfA[4], kfB[2][2], vfB[4];

    // ---- hi band (kv0 = s*32) ----
    {
        const int e = (s1 < nhi) ? s1 : nhi;
        int s = s0;
        for (; s + 1 < e; s += 2) {
            loadS(s * 32, kfA, vfA);
            loadS((s + 1) * 32, kfB, vfB);       // flies under comp(A)
            comp(s * 32, q0h, qfH, kfA, vfA, accH, mH, lH);
            comp((s + 1) * 32, q0h, qfH, kfB, vfB, accH, mH, lH);
        }
        if (s < e) {
            loadS(s * 32, kfA, vfA);
            comp(s * 32, q0h, qfH, kfA, vfA, accH, mH, lH);
        }
    }
    // ---- lo band (kv0 = (s-nhi)*32) ----
    {
        int s = (s0 > nhi) ? s0 : nhi;
        for (; s + 1 < s1; s += 2) {
            loadS((s - nhi) * 32, kfA, vfA);
            loadS((s + 1 - nhi) * 32, kfB, vfB);
            comp((s - nhi) * 32, q0l, qfL, kfA, vfA, accL, mL, lL);
            comp((s + 1 - nhi) * 32, q0l, qfL, kfB, vfB, accL, mL, lL);
        }
        if (s < s1) {
            loadS((s - nhi) * 32, kfA, vfA);
            comp((s - nhi) * 32, q0l, qfL, kfA, vfA, accL, mL, lL);
        }
    }

    // ---- write partials to LDS ----
#pragma unroll
    for (int bnd = 0; bnd < 2; ++bnd) {
        const f32x4 (&acc)[2][4] = bnd ? accL : accH;
        const float (&m2)[2] = bnd ? mL : mH;
        const float (&ls)[2] = bnd ? lL : lH;
        const int slot = bnd * 8 + w;
#pragma unroll
        for (int sub = 0; sub < 2; ++sub) {
#pragma unroll
            for (int fh = 0; fh < 4; ++fh)
                *(f32x4*)&Pacc[slot][16 * sub + lr][16 * fh + 4 * g] = acc[sub][fh];
            if (g == 0) {
                Pml[0][slot][16 * sub + lr] = m2[sub];
                Pml[1][slot][16 * sub + lr] = ls[sub];
            }
        }
    }
    __syncthreads();

    // ---- combine: 512 thr -> 2 bands x 32 q x 8 h-groups ----
    {
        const int tb = t >> 8, t2 = t & 255;
        const int qq = t2 & 31, hb = (t2 >> 5) * 8;
        float mw[8], M = NEG_INF;
#pragma unroll
        for (int wv = 0; wv < 8; ++wv) {
            mw[wv] = Pml[0][tb * 8 + wv][qq];
            M = fmaxf(M, mw[wv]);
        }
        float wgt[8], L = 0.f;
#pragma unroll
        for (int wv = 0; wv < 8; ++wv) {
            wgt[wv] = exp2f(mw[wv] - M);           // exp2(-inf)=0 for idle waves
            L += wgt[wv] * Pml[1][tb * 8 + wv][qq];
        }
        f32x4 o0 = {}, o1 = {};
#pragma unroll
        for (int wv = 0; wv < 8; ++wv) {
            f32x4 a0 = *(const f32x4*)&Pacc[tb * 8 + wv][qq][hb];
            f32x4 a1 = *(const f32x4*)&Pacc[tb * 8 + wv][qq][hb + 4];
            o0 += wgt[wv] * a0;
            o1 += wgt[wv] * a1;
        }
        const float invL = 1.f / L;
        o0 *= invL; o1 *= invL;
        const int q0 = tb ? q0l : q0h;
        float* op = out + (rowbase + q0 + qq) * 64 + hb;
        *(f32x4*)op = o0;
        *(f32x4*)(op + 4) = o1;
    }
}

// ---------------------------------------------------------------------------
extern "C" void kernel_launch(void* const* d_in, const int* in_sizes, int n_in,
                              void* d_out, int out_size, void* d_ws, size_t ws_size,
                              hipStream_t stream) {
    const float* X  = (const float*)d_in[0];
    const float* Wk = (const float*)d_in[1];
    const float* Wq = (const float*)d_in[2];
    const float* Wv = (const float*)d_in[3];

    unsigned short* Wt  = (unsigned short*)d_ws;       // 192*1024 bf16 (swizzled)
    unsigned short* Kb  = Wt + 192 * 1024;             // [16384][64] bf16
    unsigned short* Qb  = Kb + 16384 * 64;             // [16384][64] bf16
    unsigned short* Vt2 = Qb + 16384 * 64;             // [8][64][64][32] bf16 (V^T sigma)
    float* out = (float*)d_out;

    wconv_kernel<<<dim3(192), dim3(256), 0, stream>>>(Wk, Wq, Wv, Wt);
    proj_kernel<<<dim3(512), dim3(512), 0, stream>>>(X, Wt, Kb, Qb, Vt2);
    attn_kernel<<<dim3(32, 8), dim3(512), 0, stream>>>(Kb, Qb, Vt2, out);
}